// Round 1
// baseline (344.045 us; speedup 1.0000x reference)
//
#include <hip/hip_runtime.h>
#include <math.h>

// Workspace float offsets (unchanged layout, ~8.59 MB)
#define OFF_AT  0         // At  [256 h][64 r]   : A[r][h] transposed, w(h) folded
#define OFF_BMT 16384     // BmT [256 w][32 y]   : w(w) folded
#define OFF_CMT 24576     // CmT [64 r][256 h]   : mode-weight folded
#define OFF_DMT 40960     // DmT [32 y][256 w]   : y-weight folded
#define OFF_Y   49152     // Y [8][64][64 r][32 y]
#define OFF_Z   1097728   // Z [8][64][64 r][32 y]

__device__ __forceinline__ float cosT(int p) {
    // cos(pi * p / 255), exact integer argument reduction to [0, pi]
    int r = p % 510;
    if (r > 255) r = 510 - r;
    return cosf((float)r * (3.14159265358979323846f / 255.0f));
}

__global__ __launch_bounds__(256) void init_basis(float* __restrict__ ws) {
    int idx = blockIdx.x * 256 + threadIdx.x;
    if (idx < 16384) {                       // At[h][r]
        int h = idx >> 6, r = idx & 63;
        int k1 = (r < 32) ? r : r + 192;
        float we = (h == 0 || h == 255) ? 1.f : 2.f;
        ws[OFF_AT + idx] = we * cosT(k1 * h);
    } else if (idx < 24576) {                // BmT[w][y]
        int j = idx - 16384; int w = j >> 5, y = j & 31;
        float we = (w == 0 || w == 255) ? 1.f : 2.f;
        ws[OFF_BMT + j] = we * cosT(y * w);
    } else if (idx < 40960) {                // CmT[r][h]
        int j = idx - 24576; int r = j >> 8, h = j & 255;
        int k1 = (r < 32) ? r : r + 192;
        float wsl = (r == 0 || r == 63) ? 1.f : 2.f;
        ws[OFF_CMT + j] = wsl * cosT(k1 * h);
    } else if (idx < 49152) {                // DmT[y][w]
        int j = idx - 40960; int y = j >> 8, w = j & 255;
        float wy = (y == 0) ? 1.f : 2.f;
        ws[OFF_DMT + j] = wy * cosT(y * w);
    }
}

// ---------------- forward projection: Y[b,i,r,y] ----------------
// 512 threads/block, grid 512. Double-buffered 16-col x chunks, 1 barrier/chunk.
// LDS 36.9 KB -> 2 blocks/CU resident = 16 waves/CU (was 8).
__global__ __launch_bounds__(512, 4) void fwd_kernel(const float* __restrict__ x,
                                                     const float* __restrict__ ws,
                                                     float* __restrict__ Y) {
    // xs0 [256][16] @0, xs1 @4096, bs0 [16][32] @8192, bs1 @8704; T1 [256][36] @0 (reuse)
    __shared__ float lds[9216];
    const int t = threadIdx.x;
    const int bi = blockIdx.x;
    const float* xp = x + (size_t)bi * 65536;

    // staging mapping: 2 rows x float4 per thread, swizzled column slot
    const int srow = t >> 2;                    // 0..127 (rows srow, srow+128)
    const int scol = (t & 3) * 4;
    const int scolz = scol ^ (4 * ((srow >> 1) & 3));   // XOR-swizzle (row-pair keyed)

    // compute mapping: 2 h-rows x 8 y per thread
    const int hb = t & 127;
    const int y8 = (t >> 7) * 8;                // wave-uniform
    const int csw = 4 * ((hb >> 1) & 3);        // same swizzle key as staging

    float acc[2][8];
#pragma unroll
    for (int j = 0; j < 2; ++j)
#pragma unroll
        for (int yy = 0; yy < 8; ++yy) acc[j][yy] = 0.f;

    // prologue: stage chunk 0
    float4 sx0 = *(const float4*)(xp + srow * 256 + scol);
    float4 sx1 = *(const float4*)(xp + (srow + 128) * 256 + scol);
    float  sb  = ws[OFF_BMT + t];
    *(float4*)&lds[srow * 16 + scolz] = sx0;
    *(float4*)&lds[(srow + 128) * 16 + scolz] = sx1;
    lds[8192 + t] = sb;
    __syncthreads();

    for (int c = 0; c < 16; ++c) {
        const int cur = c & 1;
        if (c < 15) {   // issue next-chunk global loads early (latency hides under FMA)
            const int wofs = (c + 1) * 16;
            sx0 = *(const float4*)(xp + srow * 256 + wofs + scol);
            sx1 = *(const float4*)(xp + (srow + 128) * 256 + wofs + scol);
            sb  = ws[OFF_BMT + (c + 1) * 512 + t];
        }
        const float* xs = lds + cur * 4096;
        const float* bs = lds + 8192 + cur * 512;
#pragma unroll
        for (int w = 0; w < 16; w += 4) {
            const int wz = w ^ csw;
            float4 xa = *(const float4*)&xs[hb * 16 + wz];          // conflict-free b128
            float4 xc = *(const float4*)&xs[(hb + 128) * 16 + wz];
            const float xav[4] = {xa.x, xa.y, xa.z, xa.w};
            const float xcv[4] = {xc.x, xc.y, xc.z, xc.w};
#pragma unroll
            for (int k = 0; k < 4; ++k) {
                float4 b0 = *(const float4*)&bs[(w + k) * 32 + y8];     // wave-uniform bcast
                float4 b1 = *(const float4*)&bs[(w + k) * 32 + y8 + 4];
                const float bv[8] = {b0.x, b0.y, b0.z, b0.w, b1.x, b1.y, b1.z, b1.w};
#pragma unroll
                for (int yy = 0; yy < 8; ++yy) {
                    acc[0][yy] += xav[k] * bv[yy];
                    acc[1][yy] += xcv[k] * bv[yy];
                }
            }
        }
        if (c < 15) {   // write NEXT slot (slot last read at c-1; safe past c-1's barrier)
            const int nxt = cur ^ 1;
            *(float4*)&lds[nxt * 4096 + srow * 16 + scolz] = sx0;
            *(float4*)&lds[nxt * 4096 + (srow + 128) * 16 + scolz] = sx1;
            lds[8192 + nxt * 512 + t] = sb;
        }
        __syncthreads();    // single barrier per chunk
    }

    // write T1 into lds[0..9216) viewed as [256][36] (16B-aligned rows)
#pragma unroll
    for (int j = 0; j < 2; ++j) {
        const int row = hb + 128 * j;
        *(float4*)&lds[row * 36 + y8]     = make_float4(acc[j][0], acc[j][1], acc[j][2], acc[j][3]);
        *(float4*)&lds[row * 36 + y8 + 4] = make_float4(acc[j][4], acc[j][5], acc[j][6], acc[j][7]);
    }
    __syncthreads();

    // stage 2: Y[r][y] = sum_h At[h][r] * T1[h][y]
    const int r2 = t & 63;
    const int y4 = (t >> 6) * 4;                // wave-uniform
    float a2[4] = {0.f, 0.f, 0.f, 0.f};
    const float* At = ws + OFF_AT;
#pragma unroll 4
    for (int h = 0; h < 256; ++h) {
        const float av = At[h * 64 + r2];                    // lane-consecutive, L2-hot
        const float4 tv = *(const float4*)&lds[h * 36 + y4]; // wave-uniform bcast
        a2[0] += av * tv.x; a2[1] += av * tv.y; a2[2] += av * tv.z; a2[3] += av * tv.w;
    }
    float* Yp = Y + (size_t)bi * 2048 + r2 * 32 + y4;
    *(float4*)Yp = make_float4(a2[0], a2[1], a2[2], a2[3]);
}

// ---------------- per-mode channel mixing: Z[b,o,r,y] ----------------
// grid 1024 (64 r x 16 o-groups) -> 4 blocks/CU (was 1). W still read exactly once.
__global__ __launch_bounds__(256) void mix_kernel(const float* __restrict__ w1,
                                                  const float* __restrict__ w2,
                                                  const float* __restrict__ Yv,
                                                  float* __restrict__ Z) {
    const int r  = blockIdx.x & 63;          // mode row
    const int og = blockIdx.x >> 6;          // 0..15 o-groups of 4
    const int t  = threadIdx.x;
    const int y  = (t & 15) * 2;             // y fastest: coalesced W stream
    const int o  = og * 4 + ((t >> 4) & 3);
    const int bp = t >> 6;                   // wave id -> batch pair {bp, bp+4}

    const float* Wb = ((r < 32) ? (w1 + r * 32) : (w2 + (r - 32) * 32)) + o * 1024 + y;
    const float* Y0 = Yv + (size_t)(bp * 64) * 2048 + r * 32 + y;
    const float* Y1 = Y0 + (size_t)4 * 64 * 2048;

    float a00 = 0.f, a01 = 0.f, a10 = 0.f, a11 = 0.f;
#pragma unroll 4
    for (int i = 0; i < 64; ++i) {
        const float2 wv = *(const float2*)(Wb + (size_t)i * 65536);
        const float2 p  = *(const float2*)(Y0 + i * 2048);
        const float2 q  = *(const float2*)(Y1 + i * 2048);
        a00 += p.x * wv.x; a01 += p.y * wv.y;
        a10 += q.x * wv.x; a11 += q.y * wv.y;
    }
    float2 r0; r0.x = a00; r0.y = a01;
    float2 r1; r1.x = a10; r1.y = a11;
    *(float2*)(Z + (size_t)(bp * 64 + o) * 2048 + r * 32 + y) = r0;
    *(float2*)(Z + (size_t)((bp + 4) * 64 + o) * 2048 + r * 32 + y) = r1;
}

// ---------------- inverse projection: out[b,o,h,w] ----------------
// Same verified structure, 512 threads/block. LDS 57.9 KB -> 2 blocks/CU = 16 waves/CU.
__global__ __launch_bounds__(512, 4) void inv_kernel(const float* __restrict__ ws,
                                                     const float* __restrict__ Zv,
                                                     float* __restrict__ out) {
    __shared__ float zs[2048];     // Z slice [64 r][32 y]
    __shared__ float dmts[8192];   // DmT [32 y][256 w]
    __shared__ float t2t[4224];    // T2 transposed, half-h: [32 y][132]
    const int t = threadIdx.x;
    const int bo = blockIdx.x;
    const float* Zp = Zv + (size_t)bo * 2048;
    float* op = out + (size_t)bo * 65536;

    *(float4*)&zs[t * 4] = *(const float4*)(Zp + t * 4);
#pragma unroll
    for (int k = 0; k < 4; ++k)
        *(float4*)&dmts[k * 2048 + t * 4] = *(const float4*)(ws + OFF_DMT + k * 2048 + t * 4);
    __syncthreads();

    const int hb = t & 63;
    const int y4 = (t >> 6) * 4;   // wave-uniform, 8 groups cover 32 y
    const int wl = t & 31;
    const int hg = t >> 5;         // 0..15
    const int w0 = wl * 8;

    for (int hh = 0; hh < 2; ++hh) {
        // stage 1: T2[h][y] = sum_r CmT[r][h] * Z[r][y], h = hh*128 + {hb, hb+64}
        float a1[2][4];
#pragma unroll
        for (int j = 0; j < 2; ++j)
#pragma unroll
            for (int k = 0; k < 4; ++k) a1[j][k] = 0.f;
        const float* Cm = ws + OFF_CMT + hh * 128 + hb;
#pragma unroll 2
        for (int r = 0; r < 64; ++r) {
            const float4 zv = *(const float4*)&zs[r * 32 + y4];   // bcast
            const float av0 = Cm[r * 256];                        // lane-consecutive
            const float av1 = Cm[r * 256 + 64];
            a1[0][0] += av0 * zv.x; a1[0][1] += av0 * zv.y; a1[0][2] += av0 * zv.z; a1[0][3] += av0 * zv.w;
            a1[1][0] += av1 * zv.x; a1[1][1] += av1 * zv.y; a1[1][2] += av1 * zv.z; a1[1][3] += av1 * zv.w;
        }
#pragma unroll
        for (int j = 0; j < 2; ++j)
#pragma unroll
            for (int k = 0; k < 4; ++k)
                t2t[(y4 + k) * 132 + hb + 64 * j] = a1[j][k];   // consecutive lanes: no conflict
        __syncthreads();

        // stage 2: out[h][w] = sum_y T2[h][y] * DmT[y][w]; 8h x 8w register tile
        const int hbl = hg * 8;
        float a2[8][8];
#pragma unroll
        for (int ii = 0; ii < 8; ++ii)
#pragma unroll
            for (int ww = 0; ww < 8; ++ww) a2[ii][ww] = 0.f;
#pragma unroll 4
        for (int y = 0; y < 32; ++y) {
            const float4 ta = *(const float4*)&t2t[y * 132 + hbl];      // 2-addr bcast
            const float4 tb = *(const float4*)&t2t[y * 132 + hbl + 4];
            const float4 da = *(const float4*)&dmts[y * 256 + w0];
            const float4 db = *(const float4*)&dmts[y * 256 + w0 + 4];
            const float tv[8] = {ta.x, ta.y, ta.z, ta.w, tb.x, tb.y, tb.z, tb.w};
            const float dv[8] = {da.x, da.y, da.z, da.w, db.x, db.y, db.z, db.w};
#pragma unroll
            for (int ii = 0; ii < 8; ++ii)
#pragma unroll
                for (int ww = 0; ww < 8; ++ww)
                    a2[ii][ww] += tv[ii] * dv[ww];
        }
#pragma unroll
        for (int ii = 0; ii < 8; ++ii) {
            const int h = hh * 128 + hbl + ii;
            float* o8 = op + h * 256 + w0;
            *(float4*)o8       = make_float4(a2[ii][0], a2[ii][1], a2[ii][2], a2[ii][3]);
            *(float4*)(o8 + 4) = make_float4(a2[ii][4], a2[ii][5], a2[ii][6], a2[ii][7]);
        }
        __syncthreads();
    }
}

extern "C" void kernel_launch(void* const* d_in, const int* in_sizes, int n_in,
                              void* d_out, int out_size, void* d_ws, size_t ws_size,
                              hipStream_t stream) {
    const float* x  = (const float*)d_in[0];
    const float* w1 = (const float*)d_in[1];
    const float* w2 = (const float*)d_in[2];
    float* out = (float*)d_out;
    float* ws  = (float*)d_ws;   // needs ~8.6 MB

    hipLaunchKernelGGL(init_basis, dim3(192), dim3(256), 0, stream, ws);
    hipLaunchKernelGGL(fwd_kernel, dim3(512), dim3(512), 0, stream, x, ws, ws + OFF_Y);
    hipLaunchKernelGGL(mix_kernel, dim3(1024), dim3(256), 0, stream, w1, w2,
                       ws + OFF_Y, ws + OFF_Z);
    hipLaunchKernelGGL(inv_kernel, dim3(512), dim3(512), 0, stream, ws, ws + OFF_Z, out);
}